// Round 11
// baseline (94.963 us; speedup 1.0000x reference)
//
#include <hip/hip_runtime.h>
#include <hip/hip_bf16.h>

#define B_DIM  8
#define N_DIM  2048
#define CIN    256
#define COUT   256
#define F_DIM  8
#define EPS    1e-4f
#define CAP    128                    // max degree ~75 (mean 42, sd 6.4); R8 validated

using short8 = __attribute__((ext_vector_type(8))) short;
using f32x4  = __attribute__((ext_vector_type(4))) float;

__device__ __forceinline__ unsigned short f2bf(float f) {
    union { float f; unsigned u; } x; x.f = f;
    unsigned r = x.u + 0x7FFFu + ((x.u >> 16) & 1u);   // RNE
    return (unsigned short)(r >> 16);
}
__device__ __forceinline__ float uf(unsigned u) {
    union { unsigned u; float f; } x; x.u = u;
    return x.f;
}

// ---------------- Kernel 1: W[k,i] = sum_f pw[f] * filters[f,k,i]  (bf16 out)
__global__ __launch_bounds__(256) void wb_build(const float* __restrict__ filters,
                                                const float* __restrict__ proj_w,
                                                unsigned short* __restrict__ Wb) {
    int gid = blockIdx.x * 256 + threadIdx.x;      // = k*256 + i
    float acc = 0.f;
#pragma unroll
    for (int f = 0; f < F_DIM; ++f)
        acc += proj_w[f] * filters[f * (COUT * CIN) + gid];
    Wb[gid] = f2bf(acc);
}

// ---------------- Kernel 2: x'[m, n] = nf[m,:] @ W[n,:]^T + bias  (bf16, row-major)
__global__ __launch_bounds__(256) void xp_gemm(const float* __restrict__ nf,
                                               const unsigned short* __restrict__ Wb,
                                               const float* __restrict__ proj_b,
                                               unsigned short* __restrict__ xp) {
    const int tid  = threadIdx.x;
    const int lane = tid & 63;
    const int wv   = tid >> 6;        // 0..3
    const int m0   = blockIdx.x * 64;
    const int lrow = lane & 15;
    const int kgrp = lane >> 4;       // 0..3
    const float bias = proj_b[0];

    f32x4 acc[4][4];
#pragma unroll
    for (int a = 0; a < 4; ++a)
#pragma unroll
        for (int b = 0; b < 4; ++b)
            acc[a][b] = (f32x4){0.f, 0.f, 0.f, 0.f};

#pragma unroll
    for (int ks = 0; ks < 8; ++ks) {              // K = 8 * 32
        const int klane = ks * 32 + kgrp * 8;
        short8 af[4], bfr[4];
#pragma unroll
        for (int fm = 0; fm < 4; ++fm) {
            const float* ap = nf + (size_t)(m0 + fm * 16 + lrow) * CIN + klane;
            float4 a0 = *(const float4*)ap;
            float4 a1 = *(const float4*)(ap + 4);
            short8 t;
            t[0] = (short)f2bf(a0.x); t[1] = (short)f2bf(a0.y);
            t[2] = (short)f2bf(a0.z); t[3] = (short)f2bf(a0.w);
            t[4] = (short)f2bf(a1.x); t[5] = (short)f2bf(a1.y);
            t[6] = (short)f2bf(a1.z); t[7] = (short)f2bf(a1.w);
            af[fm] = t;
        }
#pragma unroll
        for (int fn = 0; fn < 4; ++fn) {
            const unsigned short* bp =
                Wb + (size_t)(wv * 64 + fn * 16 + lrow) * CIN + klane;
            bfr[fn] = *(const short8*)bp;         // 16B aligned
        }
#pragma unroll
        for (int fm = 0; fm < 4; ++fm)
#pragma unroll
            for (int fn = 0; fn < 4; ++fn)
                acc[fm][fn] = __builtin_amdgcn_mfma_f32_16x16x32_bf16(
                    af[fm], bfr[fn], acc[fm][fn], 0, 0, 0);
    }

    // C/D layout: col = lane&15, row = (lane>>4)*4 + r
#pragma unroll
    for (int fm = 0; fm < 4; ++fm)
#pragma unroll
        for (int fn = 0; fn < 4; ++fn) {
            const int gcol = wv * 64 + fn * 16 + lrow;
#pragma unroll
            for (int r = 0; r < 4; ++r) {
                const int grow = m0 + fm * 16 + kgrp * 4 + r;
                xp[(size_t)grow * COUT + gcol] = f2bf(acc[fm][fn][r] + bias);
            }
        }
}

// ---------------- Kernel 3a: adj row scan -> CSR (idx ushort[CAP]/row, cnt int/row).
// Pure streaming: 8 dwordx4/lane in flight, nothing behind it. Wave per row.
__global__ __launch_bounds__(256) void csr_build(const float* __restrict__ adj,
                                                 unsigned short* __restrict__ idx,
                                                 int* __restrict__ cnt) {
    const int tid   = threadIdx.x;
    const int lane  = tid & 63;
    const int wid   = tid >> 6;
    const int bid   = blockIdx.x;
    const int b     = bid & 7;
    const int i     = (bid >> 3) * 4 + wid;
    const int row_g = b * N_DIM + i;

    const float* row = adj + (size_t)row_g * N_DIM;
    float4 v[8];
#pragma unroll
    for (int q = 0; q < 8; ++q)
        v[q] = *(const float4*)(row + q * 256 + lane * 4);

    unsigned nz = 0u;
#pragma unroll
    for (int q = 0; q < 8; ++q) {
        nz |= (v[q].x != 0.f ? 1u : 0u) << (4 * q + 0);
        nz |= (v[q].y != 0.f ? 1u : 0u) << (4 * q + 1);
        nz |= (v[q].z != 0.f ? 1u : 0u) << (4 * q + 2);
        nz |= (v[q].w != 0.f ? 1u : 0u) << (4 * q + 3);
    }
    const int c = __popc(nz);

    int pre = c;
#pragma unroll
    for (int off = 1; off < 64; off <<= 1) {
        int n = __shfl_up(pre, off, 64);
        if (lane >= off) pre += n;
    }
    const int total = __shfl(pre, 63, 64);

    int p = pre - c;
    unsigned m = nz;
    unsigned short* ib = idx + (size_t)row_g * CAP;
    while (m) {
        int e = __builtin_ctz(m);
        m &= m - 1;
        if (p < CAP)
            ib[p] = (unsigned short)(((e >> 2) << 8) + (lane << 2) + (e & 3));
        ++p;
    }
    if (lane == 63) cnt[row_g] = total;
}

// ---------------- Kernel 3b: channel-sliced gather. Slice = 64 channels; per
// slice the xp working set is 16384 rows x 128 B = 2 MB -> fits EVERY XCD's L2
// (no dispatch assumptions). Slice is outermost in dispatch order. Wave = 1 row;
// quarter-waves process 4 neighbors in parallel (lane&15 owns 4 ch, uint2 load);
// 2 neighbors per quarter per iter (8 in flight). deg from cnt (exact).
__global__ __launch_bounds__(256) void csr_gather4(const unsigned short* __restrict__ idx,
                                                   const int* __restrict__ cnt,
                                                   const unsigned short* __restrict__ xp,
                                                   float* __restrict__ out) {
    const int tid   = threadIdx.x;
    const int lane  = tid & 63;
    const int wid   = tid >> 6;
    const int bid   = blockIdx.x;
    const int slice = bid >> 12;                 // 0..3 (outermost: temporal grouping)
    const int rg    = bid & 4095;
    const int row_g = rg * 4 + wid;              // 0..16383
    const int q     = lane >> 4;                 // quarter 0..3
    const int cl    = lane & 15;                 // channel-lane within quarter
    const int hi    = (q >> 1) & 1;
    const unsigned sh = (q & 1) * 16;

    const int ctrue = cnt[row_g];
    const int mcnt  = ctrue < CAP ? ctrue : CAP;
    const int b     = row_g >> 11;               // batch
    const unsigned short* ib = idx + (size_t)row_g * CAP;
    const unsigned short* xb = xp + (size_t)b * (N_DIM * COUT) + slice * 64 + cl * 4;

    float a0 = 0.f, a1 = 0.f, a2 = 0.f, a3 = 0.f;

    for (int t = 0; t < mcnt; t += 8) {
        uint4 uv = *(const uint4*)(ib + t);      // idx[t..t+7], broadcast
        unsigned w0 = hi ? uv.y : uv.x;          // ushort t+q
        unsigned w1 = hi ? uv.w : uv.z;          // ushort t+q+4
        const int j0 = (int)((w0 >> sh) & 0xFFFFu) & (N_DIM - 1);  // garbage-safe
        const int j1 = (int)((w1 >> sh) & 0xFFFFu) & (N_DIM - 1);
        uint2 g0 = *(const uint2*)(xb + (size_t)j0 * COUT);
        uint2 g1 = *(const uint2*)(xb + (size_t)j1 * COUT);
        const float s0 = (t + q) < mcnt ? 1.f : 0.f;
        const float s1 = (t + q + 4) < mcnt ? 1.f : 0.f;
        a0 = fmaf(s0, uf(g0.x << 16),         a0);
        a1 = fmaf(s0, uf(g0.x & 0xFFFF0000u), a1);
        a2 = fmaf(s0, uf(g0.y << 16),         a2);
        a3 = fmaf(s0, uf(g0.y & 0xFFFF0000u), a3);
        a0 = fmaf(s1, uf(g1.x << 16),         a0);
        a1 = fmaf(s1, uf(g1.x & 0xFFFF0000u), a1);
        a2 = fmaf(s1, uf(g1.y << 16),         a2);
        a3 = fmaf(s1, uf(g1.y & 0xFFFF0000u), a3);
    }

    // merge quarter-waves: lanes with equal (lane&15) sum across q
    a0 += __shfl_xor(a0, 16, 64); a0 += __shfl_xor(a0, 32, 64);
    a1 += __shfl_xor(a1, 16, 64); a1 += __shfl_xor(a1, 32, 64);
    a2 += __shfl_xor(a2, 16, 64); a2 += __shfl_xor(a2, 32, 64);
    a3 += __shfl_xor(a3, 16, 64); a3 += __shfl_xor(a3, 32, 64);

    if (lane < 16) {
        const float inv = __builtin_amdgcn_rcpf((float)ctrue + EPS);
        float4 o = {a0 * inv, a1 * inv, a2 * inv, a3 * inv};
        *(float4*)(out + (size_t)row_g * COUT + slice * 64 + cl * 4) = o;
    }
}

extern "C" void kernel_launch(void* const* d_in, const int* in_sizes, int n_in,
                              void* d_out, int out_size, void* d_ws, size_t ws_size,
                              hipStream_t stream) {
    const float* nf      = (const float*)d_in[0];
    const float* adj     = (const float*)d_in[1];
    const float* filters = (const float*)d_in[2];
    const float* proj_w  = (const float*)d_in[3];
    const float* proj_b  = (const float*)d_in[4];
    float* out = (float*)d_out;

    char* ws = (char*)d_ws;
    unsigned short* Wb  = (unsigned short*)ws;                       // 128 KB @ 0
    unsigned short* xp  = (unsigned short*)(ws + 131072);            // 8 MB
    int*            cnt = (int*)(ws + 131072 + 8388608);             // 64 KB
    unsigned short* idx = (unsigned short*)(ws + 131072 + 8388608 + 65536); // 4 MB

    wb_build   <<<(COUT * CIN) / 256, 256, 0, stream>>>(filters, proj_w, Wb);
    xp_gemm    <<<(B_DIM * N_DIM) / 64, 256, 0, stream>>>(nf, Wb, proj_b, xp);
    csr_build  <<<(B_DIM * N_DIM) / 4, 256, 0, stream>>>(adj, idx, cnt);
    csr_gather4<<<4 * 4096, 256, 0, stream>>>(idx, cnt, xp, out);
}

// Round 12
// 69.470 us; speedup vs baseline: 1.3670x; 1.3670x over previous
//
#include <hip/hip_runtime.h>
#include <hip/hip_bf16.h>

#define B_DIM  8
#define N_DIM  2048
#define CIN    256
#define COUT   256
#define F_DIM  8
#define EPS    1e-4f
#define CAP    128                    // max degree ~75 (mean 42, sd 6.4); R8 validated

using short8 = __attribute__((ext_vector_type(8))) short;
using f32x4  = __attribute__((ext_vector_type(4))) float;

__device__ __forceinline__ unsigned short f2bf(float f) {
    union { float f; unsigned u; } x; x.f = f;
    unsigned r = x.u + 0x7FFFu + ((x.u >> 16) & 1u);   // RNE
    return (unsigned short)(r >> 16);
}
__device__ __forceinline__ float uf(unsigned u) {
    union { unsigned u; float f; } x; x.u = u;
    return x.f;
}

// ---------------- Kernel 1: W[k,i] = sum_f pw[f] * filters[f,k,i]  (bf16 out)
__global__ __launch_bounds__(256) void wb_build(const float* __restrict__ filters,
                                                const float* __restrict__ proj_w,
                                                unsigned short* __restrict__ Wb) {
    int gid = blockIdx.x * 256 + threadIdx.x;      // = k*256 + i
    float acc = 0.f;
#pragma unroll
    for (int f = 0; f < F_DIM; ++f)
        acc += proj_w[f] * filters[f * (COUT * CIN) + gid];
    Wb[gid] = f2bf(acc);
}

// ---------------- Kernel 2a: adj row scan -> CSR (idx ushort[CAP]/row, cnt int/row).
// Runs BEFORE xp_gemm so its 134 MB adj stream can't evict xp from L2.
// Batch-pinned: b = bid&7 -> XCD b (round-robin dispatch heuristic, T1).
__global__ __launch_bounds__(256) void csr_build(const float* __restrict__ adj,
                                                 unsigned short* __restrict__ idx,
                                                 int* __restrict__ cnt) {
    const int tid   = threadIdx.x;
    const int lane  = tid & 63;
    const int wid   = tid >> 6;
    const int bid   = blockIdx.x;
    const int b     = bid & 7;
    const int i     = (bid >> 3) * 4 + wid;
    const int row_g = b * N_DIM + i;

    const float* row = adj + (size_t)row_g * N_DIM;
    float4 v[8];
#pragma unroll
    for (int q = 0; q < 8; ++q)
        v[q] = *(const float4*)(row + q * 256 + lane * 4);

    unsigned nz = 0u;
#pragma unroll
    for (int q = 0; q < 8; ++q) {
        nz |= (v[q].x != 0.f ? 1u : 0u) << (4 * q + 0);
        nz |= (v[q].y != 0.f ? 1u : 0u) << (4 * q + 1);
        nz |= (v[q].z != 0.f ? 1u : 0u) << (4 * q + 2);
        nz |= (v[q].w != 0.f ? 1u : 0u) << (4 * q + 3);
    }
    const int c = __popc(nz);

    int pre = c;
#pragma unroll
    for (int off = 1; off < 64; off <<= 1) {
        int n = __shfl_up(pre, off, 64);
        if (lane >= off) pre += n;
    }
    const int total = __shfl(pre, 63, 64);

    int p = pre - c;
    unsigned m = nz;
    unsigned short* ib = idx + (size_t)row_g * CAP;
    while (m) {
        int e = __builtin_ctz(m);
        m &= m - 1;
        if (p < CAP)
            ib[p] = (unsigned short)(((e >> 2) << 8) + (lane << 2) + (e & 3));
        ++p;
    }
    if (lane == 63) cnt[row_g] = total;
}

// ---------------- Kernel 2b: x'[m,n] = nf[m,:] @ W[n,:]^T + bias  (bf16, row-major)
// BATCH-PINNED grid: bid&7 = batch, bid>>3 = 64-row chunk. Batch b's xp slice
// (1 MB) is produced on XCD b's L2 — same XCD that will gather it.
__global__ __launch_bounds__(256) void xp_gemm(const float* __restrict__ nf,
                                               const unsigned short* __restrict__ Wb,
                                               const float* __restrict__ proj_b,
                                               unsigned short* __restrict__ xp) {
    const int tid  = threadIdx.x;
    const int lane = tid & 63;
    const int wv   = tid >> 6;        // 0..3
    const int m0   = (blockIdx.x & 7) * N_DIM + (blockIdx.x >> 3) * 64;
    const int lrow = lane & 15;
    const int kgrp = lane >> 4;       // 0..3
    const float bias = proj_b[0];

    f32x4 acc[4][4];
#pragma unroll
    for (int a = 0; a < 4; ++a)
#pragma unroll
        for (int b = 0; b < 4; ++b)
            acc[a][b] = (f32x4){0.f, 0.f, 0.f, 0.f};

#pragma unroll
    for (int ks = 0; ks < 8; ++ks) {              // K = 8 * 32
        const int klane = ks * 32 + kgrp * 8;
        short8 af[4], bfr[4];
#pragma unroll
        for (int fm = 0; fm < 4; ++fm) {
            const float* ap = nf + (size_t)(m0 + fm * 16 + lrow) * CIN + klane;
            float4 a0 = *(const float4*)ap;
            float4 a1 = *(const float4*)(ap + 4);
            short8 t;
            t[0] = (short)f2bf(a0.x); t[1] = (short)f2bf(a0.y);
            t[2] = (short)f2bf(a0.z); t[3] = (short)f2bf(a0.w);
            t[4] = (short)f2bf(a1.x); t[5] = (short)f2bf(a1.y);
            t[6] = (short)f2bf(a1.z); t[7] = (short)f2bf(a1.w);
            af[fm] = t;
        }
#pragma unroll
        for (int fn = 0; fn < 4; ++fn) {
            const unsigned short* bp =
                Wb + (size_t)(wv * 64 + fn * 16 + lrow) * CIN + klane;
            bfr[fn] = *(const short8*)bp;         // 16B aligned
        }
#pragma unroll
        for (int fm = 0; fm < 4; ++fm)
#pragma unroll
            for (int fn = 0; fn < 4; ++fn)
                acc[fm][fn] = __builtin_amdgcn_mfma_f32_16x16x32_bf16(
                    af[fm], bfr[fn], acc[fm][fn], 0, 0, 0);
    }

    // C/D layout: col = lane&15, row = (lane>>4)*4 + r
#pragma unroll
    for (int fm = 0; fm < 4; ++fm)
#pragma unroll
        for (int fn = 0; fn < 4; ++fn) {
            const int gcol = wv * 64 + fn * 16 + lrow;
#pragma unroll
            for (int r = 0; r < 4; ++r) {
                const int grow = m0 + fm * 16 + kgrp * 4 + r;
                xp[(size_t)grow * COUT + gcol] = f2bf(acc[fm][fn][r] + bias);
            }
        }
}

// ---------------- Kernel 3: gather via CSR (R8-validated scheme). Wave per row;
// lane owns 8 channels ((lane&31)*8); half-waves process even/odd neighbors.
// Working set per XCD: xp[b] 1MB + idx[b] 512KB + cnt 8KB -> L2-resident.
__global__ __launch_bounds__(256) void csr_gather(const unsigned short* __restrict__ idx,
                                                  const int* __restrict__ cnt,
                                                  const unsigned short* __restrict__ xp,
                                                  float* __restrict__ out) {
    const int tid   = threadIdx.x;
    const int lane  = tid & 63;
    const int wid   = tid >> 6;
    const int bid   = blockIdx.x;
    const int b     = bid & 7;                    // batch == XCD (matches producer)
    const int i     = (bid >> 3) * 4 + wid;
    const int row_g = b * N_DIM + i;

    const int ctrue = cnt[row_g];
    const int mcnt  = ctrue < CAP ? ctrue : CAP;
    const int h     = lane >> 5;                  // half-wave: neighbor parity
    const unsigned hsh = h * 16;

    const unsigned short* xb = xp + (size_t)b * (N_DIM * COUT) + (lane & 31) * 8;
    const unsigned short* ib = idx + (size_t)row_g * CAP;

    float a0=0.f,a1=0.f,a2=0.f,a3=0.f,a4=0.f,a5=0.f,a6=0.f,a7=0.f;

    for (int t = 0; t < mcnt; t += 16) {
        uint4 iv0 = *(const uint4*)(ib + t);      // idx[t..t+7], broadcast
        uint4 iv1 = *(const uint4*)(ib + t + 8);  // idx[t+8..t+15]
        unsigned w[8] = {iv0.x, iv0.y, iv0.z, iv0.w, iv1.x, iv1.y, iv1.z, iv1.w};
        uint4 g[8];
#pragma unroll
        for (int k = 0; k < 8; ++k) {
            int j = (int)((w[k] >> hsh) & 0xFFFFu) & (N_DIM - 1);  // garbage-safe
            g[k] = *(const uint4*)(xb + j * COUT);
        }
#pragma unroll
        for (int k = 0; k < 8; ++k) {
            const float s = (t + 2 * k + h) < mcnt ? 1.f : 0.f;
            a0 = fmaf(s, uf(g[k].x << 16),         a0);
            a1 = fmaf(s, uf(g[k].x & 0xFFFF0000u), a1);
            a2 = fmaf(s, uf(g[k].y << 16),         a2);
            a3 = fmaf(s, uf(g[k].y & 0xFFFF0000u), a3);
            a4 = fmaf(s, uf(g[k].z << 16),         a4);
            a5 = fmaf(s, uf(g[k].z & 0xFFFF0000u), a5);
            a6 = fmaf(s, uf(g[k].w << 16),         a6);
            a7 = fmaf(s, uf(g[k].w & 0xFFFF0000u), a7);
        }
    }

    // merge even/odd halves
    a0 += __shfl_xor(a0, 32, 64); a1 += __shfl_xor(a1, 32, 64);
    a2 += __shfl_xor(a2, 32, 64); a3 += __shfl_xor(a3, 32, 64);
    a4 += __shfl_xor(a4, 32, 64); a5 += __shfl_xor(a5, 32, 64);
    a6 += __shfl_xor(a6, 32, 64); a7 += __shfl_xor(a7, 32, 64);

    const float inv = __builtin_amdgcn_rcpf((float)ctrue + EPS);
    if (lane < 32) {
        float* op = out + (size_t)row_g * COUT + lane * 8;
        float4 o0 = {a0 * inv, a1 * inv, a2 * inv, a3 * inv};
        float4 o1 = {a4 * inv, a5 * inv, a6 * inv, a7 * inv};
        *(float4*)op       = o0;
        *(float4*)(op + 4) = o1;
    }
}

extern "C" void kernel_launch(void* const* d_in, const int* in_sizes, int n_in,
                              void* d_out, int out_size, void* d_ws, size_t ws_size,
                              hipStream_t stream) {
    const float* nf      = (const float*)d_in[0];
    const float* adj     = (const float*)d_in[1];
    const float* filters = (const float*)d_in[2];
    const float* proj_w  = (const float*)d_in[3];
    const float* proj_b  = (const float*)d_in[4];
    float* out = (float*)d_out;

    char* ws = (char*)d_ws;
    unsigned short* Wb  = (unsigned short*)ws;                       // 128 KB @ 0
    unsigned short* xp  = (unsigned short*)(ws + 131072);            // 8 MB
    int*            cnt = (int*)(ws + 131072 + 8388608);             // 64 KB
    unsigned short* idx = (unsigned short*)(ws + 131072 + 8388608 + 65536); // 4 MB

    // Order matters: adj stream (csr_build) runs BEFORE xp exists, so the
    // gather's working set (xp+idx+cnt, ~1.5 MB/XCD) stays L2-resident.
    wb_build  <<<(COUT * CIN) / 256, 256, 0, stream>>>(filters, proj_w, Wb);
    csr_build <<<(B_DIM * N_DIM) / 4, 256, 0, stream>>>(adj, idx, cnt);
    xp_gemm   <<<(B_DIM * N_DIM) / 64, 256, 0, stream>>>(nf, Wb, proj_b, xp);
    csr_gather<<<(B_DIM * N_DIM) / 4, 256, 0, stream>>>(idx, cnt, xp, out);
}